// Round 3
// baseline (117.286 us; speedup 1.0000x reference)
//
#include <hip/hip_runtime.h>
#include <math.h>

#define Tdim 1024
#define Hh   64

// (1/(sqrt(2)*0.8)) * log2(e) — folded into Q so attention uses exp2 directly
__device__ __constant__ float kQScale = 0.8838834764831844f * 1.4426950408889634f;

// ---------------------------------------------------------------------------
// Kernel 1: fused QKV projection. y = x @ W.T for Wq,Wk,Wv (blockIdx.y picks W).
// grid = (128 row-groups of 16, 3), block = 256.
// Q written (B,T,D) pre-scaled by kQScale (coalesced stores);
// K,V packed into KV float4 (k0,k1,v0,v1) per (bh, t).
// ---------------------------------------------------------------------------
__global__ __launch_bounds__(256) void qkv_proj(
    const float* __restrict__ x, const float* __restrict__ Wq,
    const float* __restrict__ Wk, const float* __restrict__ Wv,
    float* __restrict__ Q, float* __restrict__ KV)
{
    __shared__ float xs[16][128];     // 8 KB
    __shared__ float Wch[128][36];    // 18 KB, 32-col chunk, pad->36

    const int tid  = threadIdx.x;
    const int row0 = blockIdx.x * 16;
    const int w    = blockIdx.y;      // 0=Q 1=K 2=V

    {
        const float4* xg = reinterpret_cast<const float4*>(x + (size_t)row0 * 128);
        reinterpret_cast<float4*>(&xs[0][0])[tid]       = xg[tid];
        reinterpret_cast<float4*>(&xs[0][0])[tid + 256] = xg[tid + 256];
    }

    const float* W = (w == 0) ? Wq : (w == 1) ? Wk : Wv;

    const int j0 = tid & 31;          // cols j0 + {0,32,64,96}
    const int r0 = (tid >> 5) << 1;   // rows r0, r0+1

    float acc[2][4];
#pragma unroll
    for (int r = 0; r < 2; ++r)
#pragma unroll
        for (int c = 0; c < 4; ++c) acc[r][c] = 0.f;

    for (int ch = 0; ch < 4; ++ch) {
        __syncthreads();
#pragma unroll
        for (int s = 0; s < 4; ++s) {
            const int idx  = tid + s * 256;   // 0..1023
            const int rowW = idx >> 3;
            const int c4   = idx & 7;
            *reinterpret_cast<float4*>(&Wch[rowW][c4 * 4]) =
                reinterpret_cast<const float4*>(W + (size_t)rowW * 128 + ch * 32)[c4];
        }
        __syncthreads();

#pragma unroll
        for (int c = 0; c < 8; ++c) {
            const float4 w0 = *reinterpret_cast<const float4*>(&Wch[j0      ][c * 4]);
            const float4 w1 = *reinterpret_cast<const float4*>(&Wch[j0 + 32 ][c * 4]);
            const float4 w2 = *reinterpret_cast<const float4*>(&Wch[j0 + 64 ][c * 4]);
            const float4 w3 = *reinterpret_cast<const float4*>(&Wch[j0 + 96 ][c * 4]);
#pragma unroll
            for (int r = 0; r < 2; ++r) {
                const float4 xv = *reinterpret_cast<const float4*>(&xs[r0 + r][ch * 32 + c * 4]);
                acc[r][0] = fmaf(xv.x, w0.x, fmaf(xv.y, w0.y, fmaf(xv.z, w0.z, fmaf(xv.w, w0.w, acc[r][0]))));
                acc[r][1] = fmaf(xv.x, w1.x, fmaf(xv.y, w1.y, fmaf(xv.z, w1.z, fmaf(xv.w, w1.w, acc[r][1]))));
                acc[r][2] = fmaf(xv.x, w2.x, fmaf(xv.y, w2.y, fmaf(xv.z, w2.z, fmaf(xv.w, w2.w, acc[r][2]))));
                acc[r][3] = fmaf(xv.x, w3.x, fmaf(xv.y, w3.y, fmaf(xv.z, w3.z, fmaf(xv.w, w3.w, acc[r][3]))));
            }
        }
    }

#pragma unroll
    for (int r = 0; r < 2; ++r) {
        const int row = row0 + r0 + r;
        const int bb  = row >> 10;
        const int t   = row & 1023;
#pragma unroll
        for (int jj = 0; jj < 4; ++jj) {
            const int j = j0 + jj * 32;
            const float v = acc[r][jj];
            if (w == 0) {
                // (B,T,D) layout: coalesced (32 consecutive dwords per r,jj)
                Q[(size_t)row * 128 + j] = v * kQScale;
            } else {
                const int h  = j >> 1, dh = j & 1;
                const int bh = bb * Hh + h;
                KV[((size_t)bh * Tdim + t) * 4 + ((w == 1) ? dh : 2 + dh)] = v;
            }
        }
    }
}

// ---------------------------------------------------------------------------
// Kernel 2: causal attention, head_dim=2, no-max single-pass softmax in exp2
// domain (scores bounded |s*log2e| < ~32: no overflow in fp32).
// grid = (16 query-chunks of 64, B*H=128), block = 256 (4 lanes per query).
// Inner loop: 1 ds_read_b128 + 5 VALU + 1 v_exp per key.
// ---------------------------------------------------------------------------
__global__ __launch_bounds__(256) void attn(
    const float* __restrict__ Q, const float4* __restrict__ KV,
    float* __restrict__ O)
{
    __shared__ float4 KVs[Tdim];   // 16 KB
    const int tid   = threadIdx.x;
    const int chunk = blockIdx.x;
    const int bh    = blockIdx.y;
    const int nk    = chunk * 64 + 64;

    const float4* KVg = KV + (size_t)bh * Tdim;
    for (int i = tid; i < nk; i += 256) KVs[i] = KVg[i];
    __syncthreads();

    const int t   = chunk * 64 + (tid >> 2);
    const int sub = tid & 3;
    const int b   = bh >> 6, h = bh & 63;
    const float2 q = *reinterpret_cast<const float2*>(
        Q + (size_t)(b * Tdim + t) * 128 + h * 2);

    float l = 0.f, a0 = 0.f, a1 = 0.f;
#pragma unroll 4
    for (int k = sub; k <= t; k += 4) {
        const float4 kv = KVs[k];
        const float p = exp2f(fmaf(q.x, kv.x, q.y * kv.y));
        l  += p;
        a0 = fmaf(p, kv.z, a0);
        a1 = fmaf(p, kv.w, a1);
    }

    l  += __shfl_xor(l, 1);  l  += __shfl_xor(l, 2);
    a0 += __shfl_xor(a0, 1); a0 += __shfl_xor(a0, 2);
    a1 += __shfl_xor(a1, 1); a1 += __shfl_xor(a1, 2);

    if (sub == 0) {
        const float rl = 1.0f / l;
        float* Op = O + (size_t)(b * Tdim + t) * 128 + h * 2;
        Op[0] = a0 * rl;
        Op[1] = a1 * rl;
    }
}

// ---------------------------------------------------------------------------
// Kernel 3: output projection out = O @ Wo.T (same structure as qkv_proj).
// grid = 128, block = 256.
// ---------------------------------------------------------------------------
__global__ __launch_bounds__(256) void out_proj(
    const float* __restrict__ Oin, const float* __restrict__ Wo,
    float* __restrict__ out)
{
    __shared__ float xs[16][128];
    __shared__ float Wch[128][36];

    const int tid  = threadIdx.x;
    const int row0 = blockIdx.x * 16;

    {
        const float4* xg = reinterpret_cast<const float4*>(Oin + (size_t)row0 * 128);
        reinterpret_cast<float4*>(&xs[0][0])[tid]       = xg[tid];
        reinterpret_cast<float4*>(&xs[0][0])[tid + 256] = xg[tid + 256];
    }

    const int j0 = tid & 31;
    const int r0 = (tid >> 5) << 1;

    float acc[2][4];
#pragma unroll
    for (int r = 0; r < 2; ++r)
#pragma unroll
        for (int c = 0; c < 4; ++c) acc[r][c] = 0.f;

    for (int ch = 0; ch < 4; ++ch) {
        __syncthreads();
#pragma unroll
        for (int s = 0; s < 4; ++s) {
            const int idx  = tid + s * 256;
            const int rowW = idx >> 3;
            const int c4   = idx & 7;
            *reinterpret_cast<float4*>(&Wch[rowW][c4 * 4]) =
                reinterpret_cast<const float4*>(Wo + (size_t)rowW * 128 + ch * 32)[c4];
        }
        __syncthreads();

#pragma unroll
        for (int c = 0; c < 8; ++c) {
            const float4 w0 = *reinterpret_cast<const float4*>(&Wch[j0      ][c * 4]);
            const float4 w1 = *reinterpret_cast<const float4*>(&Wch[j0 + 32 ][c * 4]);
            const float4 w2 = *reinterpret_cast<const float4*>(&Wch[j0 + 64 ][c * 4]);
            const float4 w3 = *reinterpret_cast<const float4*>(&Wch[j0 + 96 ][c * 4]);
#pragma unroll
            for (int r = 0; r < 2; ++r) {
                const float4 xv = *reinterpret_cast<const float4*>(&xs[r0 + r][ch * 32 + c * 4]);
                acc[r][0] = fmaf(xv.x, w0.x, fmaf(xv.y, w0.y, fmaf(xv.z, w0.z, fmaf(xv.w, w0.w, acc[r][0]))));
                acc[r][1] = fmaf(xv.x, w1.x, fmaf(xv.y, w1.y, fmaf(xv.z, w1.z, fmaf(xv.w, w1.w, acc[r][1]))));
                acc[r][2] = fmaf(xv.x, w2.x, fmaf(xv.y, w2.y, fmaf(xv.z, w2.z, fmaf(xv.w, w2.w, acc[r][2]))));
                acc[r][3] = fmaf(xv.x, w3.x, fmaf(xv.y, w3.y, fmaf(xv.z, w3.z, fmaf(xv.w, w3.w, acc[r][3]))));
            }
        }
    }

#pragma unroll
    for (int r = 0; r < 2; ++r) {
        const int row = row0 + r0 + r;
#pragma unroll
        for (int jj = 0; jj < 4; ++jj) {
            const int j = j0 + jj * 32;
            out[(size_t)row * 128 + j] = acc[r][jj];
        }
    }
}

extern "C" void kernel_launch(void* const* d_in, const int* in_sizes, int n_in,
                              void* d_out, int out_size, void* d_ws, size_t ws_size,
                              hipStream_t stream) {
    const float* x  = (const float*)d_in[0];
    const float* Wq = (const float*)d_in[1];
    const float* Wk = (const float*)d_in[2];
    const float* Wv = (const float*)d_in[3];
    const float* Wo = (const float*)d_in[4];
    float* out = (float*)d_out;

    // workspace: Q (B,T,D) 1MB | KV (B,H,T,4) 2MB | O (B,T,D) 1MB
    float* ws = (float*)d_ws;
    float* Q  = ws;
    float* KV = ws + 262144;
    float* O  = ws + 786432;

    qkv_proj<<<dim3(128, 3), 256, 0, stream>>>(x, Wq, Wk, Wv, Q, KV);
    attn<<<dim3(16, 128), 256, 0, stream>>>(Q, (const float4*)KV, O);
    out_proj<<<128, 256, 0, stream>>>(O, Wo, out);
}